// Round 1
// baseline (1343.830 us; speedup 1.0000x reference)
//
#include <hip/hip_runtime.h>

#define NF 128   // feature dim F
#define KN 32    // neighbors K
#define NH 4     // heads H
#define HD 256   // H*D
#define NC 40    // classes C
#define SH 257   // padded LDS stride for Hs (breaks stride-256 bank conflicts)

__global__ __launch_bounds__(128, 2)
void gat_fused(const float* __restrict__ nodef,
               const float* __restrict__ neigh,
               const float* __restrict__ W,
               const float* __restrict__ a_src,
               const float* __restrict__ a_dst,
               const float* __restrict__ cls_w,
               float* __restrict__ out)
{
    __shared__ __align__(16) float Xs[33 * NF];     // row 0 = center, 1..32 = neighbors
    __shared__ float Hs[33 * SH];                   // H = X @ W   (row 0 = h_i)
    __shared__ float e_lds[33 * NH];                // e_i (m=0) and e_j (m=1..32)
    __shared__ float alpha_lds[KN * NH];
    __shared__ float part_y[2 * NC];

    const int n    = blockIdx.x;
    const int t    = threadIdx.x;
    const int lane = t & 63;
    const int wv   = t >> 6;        // wave id 0/1
    const int c0   = t;             // column set 1: heads 0 (wave0) / 1 (wave1)
    const int c1   = t + 128;       // column set 2: heads 2 (wave0) / 3 (wave1)

    // ---- Phase A: stage center + 32 neighbor feature rows into LDS ----
    {
        const float4* src_c = (const float4*)(nodef + (size_t)n * NF);
        const float4* src_n = (const float4*)(neigh + (size_t)n * KN * NF);
        float4* dst = (float4*)Xs;
        for (int idx = t; idx < 33 * (NF / 4); idx += 128) {
            int m  = idx >> 5;      // 32 float4 per 128-float row
            int c4 = idx & 31;
            dst[idx] = (m == 0) ? src_c[c4] : src_n[(m - 1) * 32 + c4];
        }
    }
    __syncthreads();

    // ---- Phase B: H = X @ W  (X:[33,128] @ W:[128,256]) ----
    // Each thread accumulates all 33 rows for its 2 columns; X values are
    // LDS broadcasts, W columns are coalesced global loads (L2-resident).
    float acc0[33], acc1[33];
    #pragma unroll
    for (int m = 0; m < 33; ++m) { acc0[m] = 0.f; acc1[m] = 0.f; }

    #pragma unroll 2
    for (int k4 = 0; k4 < NF / 4; ++k4) {
        const int k = k4 * 4;
        float wa0 = W[(k+0)*HD + c0], wb0 = W[(k+0)*HD + c1];
        float wa1 = W[(k+1)*HD + c0], wb1 = W[(k+1)*HD + c1];
        float wa2 = W[(k+2)*HD + c0], wb2 = W[(k+2)*HD + c1];
        float wa3 = W[(k+3)*HD + c0], wb3 = W[(k+3)*HD + c1];
        const float4* X4 = (const float4*)Xs;
        #pragma unroll
        for (int m = 0; m < 33; ++m) {
            float4 xv = X4[m * 32 + k4];
            acc0[m] = fmaf(xv.x, wa0, acc0[m]);
            acc0[m] = fmaf(xv.y, wa1, acc0[m]);
            acc0[m] = fmaf(xv.z, wa2, acc0[m]);
            acc0[m] = fmaf(xv.w, wa3, acc0[m]);
            acc1[m] = fmaf(xv.x, wb0, acc1[m]);
            acc1[m] = fmaf(xv.y, wb1, acc1[m]);
            acc1[m] = fmaf(xv.z, wb2, acc1[m]);
            acc1[m] = fmaf(xv.w, wb3, acc1[m]);
        }
    }

    // ---- Phase C: store H to LDS; e[m][h] via 64-lane shuffle reduction ----
    // Each wave's c0 columns span exactly one head => reduce over the wave.
    const float as0 = a_src[c0], ad0 = a_dst[c0];
    const float as1 = a_src[c1], ad1 = a_dst[c1];
    #pragma unroll
    for (int m = 0; m < 33; ++m) {
        Hs[m * SH + c0] = acc0[m];
        Hs[m * SH + c1] = acc1[m];
        float p0 = acc0[m] * (m == 0 ? as0 : ad0);
        float p1 = acc1[m] * (m == 0 ? as1 : ad1);
        #pragma unroll
        for (int s = 1; s < 64; s <<= 1) {
            p0 += __shfl_xor(p0, s);
            p1 += __shfl_xor(p1, s);
        }
        if (lane == 0) {
            e_lds[m * NH + wv]     = p0;   // head wv   (c0 set)
            e_lds[m * NH + wv + 2] = p1;   // head wv+2 (c1 set)
        }
    }
    __syncthreads();

    // ---- Phase D: LeakyReLU + softmax over K per head (32-lane groups) ----
    {
        int h  = t >> 5;           // lanes 0-31 of each wave = one head group
        int kk = t & 31;
        float z = e_lds[h] + e_lds[(1 + kk) * NH + h];
        float l = z > 0.f ? z : 0.2f * z;
        float mx = l;
        #pragma unroll
        for (int s = 1; s < 32; s <<= 1) mx = fmaxf(mx, __shfl_xor(mx, s));
        float p = expf(l - mx);
        float sm = p;
        #pragma unroll
        for (int s = 1; s < 32; s <<= 1) sm += __shfl_xor(sm, s);
        alpha_lds[kk * NH + h] = p / sm;
    }
    __syncthreads();

    // ---- Phase E: out[c] = sum_k alpha[k][h(c)] * H[k][c] ----
    const int h0 = wv;
    const int h1 = wv + 2;
    float o0 = 0.f, o1 = 0.f;
    #pragma unroll
    for (int kk = 0; kk < KN; ++kk) {
        float a0 = alpha_lds[kk * NH + h0];
        float a1 = alpha_lds[kk * NH + h1];
        o0 = fmaf(a0, Hs[(1 + kk) * SH + c0], o0);
        o1 = fmaf(a1, Hs[(1 + kk) * SH + c1], o1);
    }
    // reuse Hs row 0 (h_i, no longer needed) as the aggregated [256] vector
    Hs[c0] = o0;
    Hs[c1] = o1;
    __syncthreads();

    // ---- Phase F: y = outv @ cls_w  ([256] @ [256,40]), split over 2 waves ----
    {
        int cbase = wv * 128;
        if (lane < NC) {
            float y = 0.f;
            #pragma unroll 4
            for (int cc = 0; cc < 128; ++cc) {
                int c = cbase + cc;
                y = fmaf(Hs[c], cls_w[c * NC + lane], y);
            }
            part_y[wv * NC + lane] = y;
        }
    }
    __syncthreads();
    if (t < NC) out[(size_t)n * NC + t] = part_y[t] + part_y[NC + t];
}

extern "C" void kernel_launch(void* const* d_in, const int* in_sizes, int n_in,
                              void* d_out, int out_size, void* d_ws, size_t ws_size,
                              hipStream_t stream) {
    const float* nodef  = (const float*)d_in[0];
    const float* neigh  = (const float*)d_in[1];
    const float* W      = (const float*)d_in[2];
    const float* a_src  = (const float*)d_in[3];
    const float* a_dst  = (const float*)d_in[4];
    const float* cls_w  = (const float*)d_in[5];
    float* out = (float*)d_out;

    const int n_nodes = in_sizes[0] / NF;   // 20000
    hipLaunchKernelGGL(gat_fused, dim3(n_nodes), dim3(128), 0, stream,
                       nodef, neigh, W, a_src, a_dst, cls_w, out);
}

// Round 2
// 165.841 us; speedup vs baseline: 8.1031x; 8.1031x over previous
//
#include <hip/hip_runtime.h>

#define KN 32      // neighbors
#define NF 128     // feature dim
#define NH 4       // heads
#define HD 256     // H*D
#define NC 40      // classes
#define NPB 8      // nodes per block
#define XSS 136    // padded LDS stride for Xs rows (float4-aligned, conflict-free)

// ---- prep: w_src[h][f] = sum_d W[f][h*64+d]*a_src[h][d]; same for dst ----
__global__ void gat_prep(const float* __restrict__ W,
                         const float* __restrict__ a_src,
                         const float* __restrict__ a_dst,
                         float* __restrict__ ws)
{
    int g = blockIdx.x * blockDim.x + threadIdx.x;
    if (g >= 1024) return;
    int which = g >> 9;            // 0 = src, 1 = dst
    int h = (g >> 7) & 3;
    int f = g & 127;
    const float* a = which ? a_dst : a_src;
    float s = 0.f;
    #pragma unroll 8
    for (int d = 0; d < 64; ++d)
        s = fmaf(W[f * HD + h * 64 + d], a[h * 64 + d], s);
    ws[g] = s;
}

__global__ __launch_bounds__(256, 3)
void gat_main(const float* __restrict__ nodef,
              const float* __restrict__ neigh,
              const float* __restrict__ W,
              const float* __restrict__ cls_w,
              const float* __restrict__ ws,
              float* __restrict__ out,
              int n_nodes)
{
    __shared__ __align__(16) float Xs[KN * XSS];         // neighbor tile (also reused as outv)
    __shared__ __align__(16) float xi_lds[NF];
    __shared__ __align__(16) float e_lds[KN * NH];
    __shared__ float ei_lds[NH];
    __shared__ __align__(16) float alpha_l[2][KN][2];    // [hpair][k][h&1]
    __shared__ __align__(16) float zl[NPB][NH][NF];      // aggregated features per head

    const int t  = threadIdx.x;
    const int kq = t >> 3;      // neighbor row 0..31
    const int fq = t & 7;       // feature-slice id

    // cache w_dst slices in registers: wd[h][j] = wdst[h*128 + fq*4 + 32j .. +3]
    const float* wsrc = ws;
    const float* wdst = ws + 512;
    float4 wd[4][4];
    #pragma unroll
    for (int h = 0; h < 4; ++h)
        #pragma unroll
        for (int j = 0; j < 4; ++j)
            wd[h][j] = *(const float4*)&wdst[h * NF + fq * 4 + 32 * j];

    const int node0 = blockIdx.x * NPB;
    if (node0 >= n_nodes) return;

    // prologue: load node0's tile into registers (coalesced: 8 lanes x 16B = 128B/row)
    float4 xv[4], xiv;
    {
        const float4* src = (const float4*)(neigh + ((size_t)node0 * KN + kq) * NF);
        #pragma unroll
        for (int j = 0; j < 4; ++j) xv[j] = src[fq + 8 * j];
        if (t < 32) xiv = ((const float4*)(nodef + (size_t)node0 * NF))[t];
    }

    for (int i = 0; i < NPB; ++i) {
        __syncthreads();                       // Xs / alpha free for reuse
        #pragma unroll
        for (int j = 0; j < 4; ++j)
            *(float4*)&Xs[kq * XSS + fq * 4 + 32 * j] = xv[j];
        if (t < 32) *(float4*)&xi_lds[t * 4] = xiv;
        __syncthreads();

        // ---- e_j partial dots straight from registers ----
        float s0 = 0.f, s1 = 0.f, s2 = 0.f, s3 = 0.f;
        #pragma unroll
        for (int j = 0; j < 4; ++j) {
            s0 += xv[j].x * wd[0][j].x + xv[j].y * wd[0][j].y + xv[j].z * wd[0][j].z + xv[j].w * wd[0][j].w;
            s1 += xv[j].x * wd[1][j].x + xv[j].y * wd[1][j].y + xv[j].z * wd[1][j].z + xv[j].w * wd[1][j].w;
            s2 += xv[j].x * wd[2][j].x + xv[j].y * wd[2][j].y + xv[j].z * wd[2][j].z + xv[j].w * wd[2][j].w;
            s3 += xv[j].x * wd[3][j].x + xv[j].y * wd[3][j].y + xv[j].z * wd[3][j].z + xv[j].w * wd[3][j].w;
        }

        // ---- prefetch next node (issue-early; lands under softmax/agg phases) ----
        if (i + 1 < NPB && node0 + i + 1 < n_nodes) {
            const float4* src = (const float4*)(neigh + ((size_t)(node0 + i + 1) * KN + kq) * NF);
            #pragma unroll
            for (int j = 0; j < 4; ++j) xv[j] = src[fq + 8 * j];
            if (t < 32) xiv = ((const float4*)(nodef + (size_t)(node0 + i + 1) * NF))[t];
        }

        // reduce e_j over the 8 feature-slices
        #pragma unroll
        for (int st = 1; st < 8; st <<= 1) {
            s0 += __shfl_xor(s0, st);
            s1 += __shfl_xor(s1, st);
            s2 += __shfl_xor(s2, st);
            s3 += __shfl_xor(s3, st);
        }
        if (fq == 0) *(float4*)&e_lds[kq * 4] = make_float4(s0, s1, s2, s3);

        // ---- e_i ----
        if (t < 128) {
            int h = t >> 5, j = t & 31;
            float p = 0.f;
            #pragma unroll
            for (int m = 0; m < 4; ++m)
                p = fmaf(xi_lds[j + 32 * m], wsrc[h * NF + j + 32 * m], p);
            #pragma unroll
            for (int st = 1; st < 32; st <<= 1) p += __shfl_xor(p, st);
            if (j == 0) ei_lds[h] = p;
        }
        __syncthreads();

        // ---- LeakyReLU + softmax over K per head ----
        if (t < 128) {
            int h = t >> 5, k = t & 31;
            float z = ei_lds[h] + e_lds[k * 4 + h];
            float l = z > 0.f ? z : 0.2f * z;
            float mx = l;
            #pragma unroll
            for (int st = 1; st < 32; st <<= 1) mx = fmaxf(mx, __shfl_xor(mx, st));
            float p = __expf(l - mx);
            float sm = p;
            #pragma unroll
            for (int st = 1; st < 32; st <<= 1) sm += __shfl_xor(sm, st);
            alpha_l[h >> 1][k][h & 1] = p / sm;
        }
        __syncthreads();

        // ---- feature aggregation: z[h][f] = sum_k alpha[k][h] * x[k][f] ----
        {
            int f = t & 127, hp = t >> 7;
            float z0 = 0.f, z1 = 0.f;
            #pragma unroll 8
            for (int k = 0; k < KN; ++k) {
                float2 a2 = *(const float2*)&alpha_l[hp][k][0];
                float x = Xs[k * XSS + f];
                z0 = fmaf(a2.x, x, z0);
                z1 = fmaf(a2.y, x, z1);
            }
            zl[i][hp * 2 + 0][f] = z0;
            zl[i][hp * 2 + 1][f] = z1;
        }
    }
    __syncthreads();

    // ---- batched out = z @ W (8 nodes at once, W reads coalesced & L2-hot) ----
    float* outv = Xs;                       // Xs is dead; reuse as outv[NPB][HD]
    {
        const int c = t;
        const int hh = c >> 6;
        float acc[NPB];
        #pragma unroll
        for (int i = 0; i < NPB; ++i) acc[i] = 0.f;
        #pragma unroll 4
        for (int f4 = 0; f4 < 32; ++f4) {
            float wA = W[(4 * f4 + 0) * HD + c];
            float wB = W[(4 * f4 + 1) * HD + c];
            float wC = W[(4 * f4 + 2) * HD + c];
            float wD = W[(4 * f4 + 3) * HD + c];
            #pragma unroll
            for (int i = 0; i < NPB; ++i) {
                float4 zv = *(const float4*)&zl[i][hh][f4 * 4];
                acc[i] = fmaf(wA, zv.x, acc[i]);
                acc[i] = fmaf(wB, zv.y, acc[i]);
                acc[i] = fmaf(wC, zv.z, acc[i]);
                acc[i] = fmaf(wD, zv.w, acc[i]);
            }
        }
        #pragma unroll
        for (int i = 0; i < NPB; ++i) outv[i * HD + c] = acc[i];
    }
    __syncthreads();

    // ---- classifier: y[n][cls] = sum_c outv[n][c] * cls_w[c][cls] ----
    #pragma unroll
    for (int rep = 0; rep < 2; ++rep) {
        int p = t + rep * 256;
        if (p < NPB * NC) {
            int ni = p / NC, cls = p - ni * NC;
            float y = 0.f;
            #pragma unroll 8
            for (int c2 = 0; c2 < HD; ++c2)
                y = fmaf(outv[ni * HD + c2], cls_w[c2 * NC + cls], y);
            if (node0 + ni < n_nodes)
                out[(size_t)(node0 + ni) * NC + cls] = y;
        }
    }
}

extern "C" void kernel_launch(void* const* d_in, const int* in_sizes, int n_in,
                              void* d_out, int out_size, void* d_ws, size_t ws_size,
                              hipStream_t stream) {
    const float* nodef = (const float*)d_in[0];
    const float* neigh = (const float*)d_in[1];
    const float* W     = (const float*)d_in[2];
    const float* a_src = (const float*)d_in[3];
    const float* a_dst = (const float*)d_in[4];
    const float* cls_w = (const float*)d_in[5];
    float* out = (float*)d_out;
    float* ws  = (float*)d_ws;

    const int n_nodes = in_sizes[0] / NF;   // 20000

    hipLaunchKernelGGL(gat_prep, dim3(4), dim3(256), 0, stream, W, a_src, a_dst, ws);
    hipLaunchKernelGGL(gat_main, dim3((n_nodes + NPB - 1) / NPB), dim3(256), 0, stream,
                       nodef, neigh, W, cls_w, ws, out, n_nodes);
}